// Round 13
// baseline (233.769 us; speedup 1.0000x reference)
//
#include <hip/hip_runtime.h>

typedef __attribute__((ext_vector_type(8))) short bf16x8;
typedef __attribute__((ext_vector_type(4))) float f32x4;

#define FROW   4224                     // 66 cols * 64 B per LDS feature row
#define FBUF4  25344                    // 6 rows (4-row block + halo)
#define BTRIO  12288                    // 3 taps * 4096 B
#define LDS_T2 (2 * FBUF4 + 2 * BTRIO)  // 75264 B -> 2 blocks/CU

static __device__ __forceinline__ unsigned short f2bf(float f) {
  union { float f; unsigned u; } v; v.f = f;
  unsigned r = v.u + 0x7fffu + ((v.u >> 16) & 1u);
  return (unsigned short)(r >> 16);
}

static __device__ __forceinline__ void gload16(const void* g, void* l) {
  __builtin_amdgcn_global_load_lds(
      (const __attribute__((address_space(1))) void*)g,
      (__attribute__((address_space(3))) void*)l, 16, 0, 0);
}

// ---------------- kernel P: pack weights ----------------
// wpk: [it(126 = c2*9+tap)][co(64)][slot(4)][8ci] bf16, slot' = slot ^ ((co>>1)&3)
__global__ void pack_w_k(const float* __restrict__ sb, const float* __restrict__ ss,
                         const float* __restrict__ cf, unsigned short* __restrict__ wpk) {
  int idx = blockIdx.x * 256 + threadIdx.x;
  if (idx >= 126 * 64 * 32) return;
  int e = idx & 7;
  int q = (idx >> 3) & 3;
  int co = (idx >> 5) & 63;
  int rest = idx >> 11;
  int tap = rest % 9;
  int c2 = rest / 9;
  int c = c2 >> 1, half = c2 & 1;
  int ci = half * 32 + q * 8 + e;
  int kh = tap / 3, kw = tap % 3;
  int wi = ((co * 64 + ci) * 3 + kh) * 3 + kw;
  float v;
  if (c == 0) {
    v = sb[wi];
  } else {
    int s = (c - 1) / 3, g = (c - 1) % 3;
    v = cf[(s * 36864 + wi) * 3 + g] * ss[wi];
  }
  wpk[((c2 * 9 + tap) * 64 + co) * 32 + ((q ^ ((co >> 1) & 3)) << 3) + e] = f2bf(v);
}

// ---------------- kernel G: fused featgen + implicit GEMM, 2 blocks/CU ----------------
// grid (32 b, 16 hg) = 512 blocks = 2/CU (LDS 75.3 KB). 4 waves; wave wid owns
// image row h0+wid: M=64 px x N=64 co, all 9 taps. Features are computed
// IN-KERNEL from x (no fg intermediate): per chunk each thread does
// 6 rows x 8 ci -> one ds_write_b128/row into the swizzled layout, spread
// 2 rows per kh phase. B staged from wpk as 3-tap trios via global_load_lds.
__global__ __launch_bounds__(256, 2) void gemm_k(
    const float* __restrict__ x, const unsigned short* __restrict__ wpk,
    const float* __restrict__ bias, float* __restrict__ out) {
  extern __shared__ __align__(16) char smem[];
  const int b = blockIdx.x;
  const int h0 = blockIdx.y * 4;
  const int tid = threadIdx.x;
  const int lane = tid & 63;
  const int wid = tid >> 6;          // 0..3
  const int l15 = lane & 15;
  const int lg = lane >> 4;
  const char* wpkB = (const char*)wpk;

  // featgen thread map: w = tid&63 (lane=w: coalesced), q = ci-quad = tid>>6
  const int fw = tid & 63;
  const int fq = tid >> 6;
  const int fcol = fw + 1;                               // LDS col (halo 0/65)
  const int fsl16 = (fq ^ ((fcol >> 1) & 3)) << 4;       // swizzled slot byte-off

  // zero never-staged bytes: halo cols + out-of-range rows (both feat buffers)
  for (int i = tid; i < 2 * FBUF4 / 4; i += 256) {
    int off = i * 4;
    int off2 = (off >= FBUF4) ? off - FBUF4 : off;
    int row = off2 / FROW;
    int cb = off2 - row * FROW;
    int hh = h0 - 1 + row;
    bool staged = ((unsigned)hh < 64u) && (cb >= 64) && (cb < 4160);
    if (!staged) ((int*)smem)[i] = 0;
  }

  // hoisted swizzled LDS offsets
  int aoff[4][3], boff[4];
#pragma unroll
  for (int cf = 0; cf < 4; ++cf) {
#pragma unroll
    for (int kw = 0; kw < 3; ++kw) {
      int col = cf * 16 + l15 + kw;
      aoff[cf][kw] = col * 64 + ((lg ^ ((col >> 1) & 3)) << 4);
    }
    int co = cf * 16 + l15;
    boff[cf] = co * 64 + ((lg ^ ((co >> 1) & 3)) << 4);
  }

  // stage B trio for (chunk cn, kh khn) into bdst: 12 gload16 over 4 waves
#define STAGE_TRIO(cn, khn, bdst)                                                \
  _Pragma("unroll")                                                              \
  for (int i = 0; i < 3; ++i) {                                                  \
    int u = i * 4 + wid;                                                         \
    gload16(wpkB + (size_t)((cn) * 9 + (khn) * 3 + (u >> 2)) * 4096 +            \
                (u & 3) * 1024 + lane * 16,                                      \
            (bdst) + (u >> 2) * 4096 + (u & 3) * 1024);                          \
  }

  // featgen phase: rows 2p, 2p+1 of chunk cn into fdst (8 x-loads -> 1 b128 write)
#define FEATGEN_P(cn, p, fdst)                                                   \
  {                                                                              \
    const int c_ = (cn) >> 1, half_ = (cn) & 1;                                  \
    const float* xq_ = x + ((size_t)(b * 64 + half_ * 32 + fq * 8) * 64) * 64 + fw; \
    _Pragma("unroll")                                                            \
    for (int rr = 0; rr < 2; ++rr) {                                             \
      int r = (p) * 2 + rr;                                                      \
      int hh = h0 - 1 + r;                                                       \
      if ((unsigned)hh < 64u) {                                                  \
        bf16x8 pk;                                                               \
        _Pragma("unroll")                                                        \
        for (int e = 0; e < 8; ++e) {                                            \
          float v = xq_[(size_t)e * 4096 + hh * 64];                             \
          float val;                                                             \
          if (c_ == 0)      val = v / (1.0f + __expf(-v));                       \
          else if (c_ == 1) val = __cosf(v);                                     \
          else if (c_ == 2) val = __cosf(2.0f * v);                              \
          else if (c_ == 3) val = __cosf(3.0f * v);                              \
          else if (c_ == 4) val = __sinf(v);                                     \
          else if (c_ == 5) val = __sinf(2.0f * v);                              \
          else              val = __sinf(3.0f * v);                              \
          pk[e] = (short)f2bf(val);                                              \
        }                                                                        \
        *(bf16x8*)((fdst) + r * FROW + fcol * 64 + fsl16) = pk;                  \
      }                                                                          \
    }                                                                            \
  }

  // prologue: features chunk 0 (all 3 phases) + B trio (0,0)
#pragma unroll
  for (int p = 0; p < 3; ++p) { FEATGEN_P(0, p, smem) }
  STAGE_TRIO(0, 0, smem + 2 * FBUF4)
  __syncthreads();

  f32x4 acc[4][4];
#pragma unroll
  for (int cfi = 0; cfi < 4; ++cfi)
#pragma unroll
    for (int nf = 0; nf < 4; ++nf)
#pragma unroll
      for (int qq = 0; qq < 4; ++qq) acc[cfi][nf][qq] = 0.0f;

  for (int c2 = 0; c2 < 14; ++c2) {
    const char* f = smem + ((c2 & 1) ? FBUF4 : 0);
    char* fnext = smem + (((c2 + 1) & 1) ? FBUF4 : 0);
#pragma unroll
    for (int kh = 0; kh < 3; ++kh) {
      const int khg = c2 * 3 + kh;
      const char* bb = smem + 2 * FBUF4 + ((khg & 1) ? BTRIO : 0);
      if (khg < 41) {
        char* bnext = smem + 2 * FBUF4 + (((khg + 1) & 1) ? BTRIO : 0);
        const int cn = (khg + 1) / 3, khn = (khg + 1) % 3;
        STAGE_TRIO(cn, khn, bnext)
      }
      if (c2 < 13) { FEATGEN_P(c2 + 1, kh, fnext) }

      const char* frow = f + (wid + kh) * FROW;
#pragma unroll
      for (int kw = 0; kw < 3; ++kw) {
        bf16x8 A[4], Bv[4];
#pragma unroll
        for (int cfi = 0; cfi < 4; ++cfi)
          A[cfi] = *(const bf16x8*)(frow + aoff[cfi][kw]);
#pragma unroll
        for (int nf = 0; nf < 4; ++nf)
          Bv[nf] = *(const bf16x8*)(bb + kw * 4096 + boff[nf]);
#pragma unroll
        for (int cfi = 0; cfi < 4; ++cfi)
#pragma unroll
          for (int nf = 0; nf < 4; ++nf)
            acc[cfi][nf] = __builtin_amdgcn_mfma_f32_16x16x32_bf16(
                A[cfi], Bv[nf], acc[cfi][nf], 0, 0, 0);
      }
      __syncthreads();
    }
  }
#undef STAGE_TRIO
#undef FEATGEN_P

  // epilogue: direct store. C/D: col(l15)=co, row=lg*4+reg = pixel w
  const int h = h0 + wid;
#pragma unroll
  for (int cfi = 0; cfi < 4; ++cfi) {
    int w4 = cfi * 16 + (lg << 2);
#pragma unroll
    for (int nf = 0; nf < 4; ++nf) {
      int co = nf * 16 + l15;
      float bv = bias[co];
      f32x4 v = acc[cfi][nf];
      f32x4 res;
      res[0] = v[0] + bv; res[1] = v[1] + bv; res[2] = v[2] + bv; res[3] = v[3] + bv;
      *(f32x4*)(out + ((size_t)(b * 64 + co) * 64 + h) * 64 + w4) = res;
    }
  }
}

// ---------------- fallback: naive fp32 direct (if ws too small) ----------------
__global__ void naive_k(const float* __restrict__ x, const float* __restrict__ sb,
                        const float* __restrict__ ss, const float* __restrict__ cf,
                        const float* __restrict__ bias, float* __restrict__ out) {
  int idx = blockIdx.x * 256 + threadIdx.x;
  if (idx >= 32 * 64 * 64 * 64) return;
  int w = idx & 63, h = (idx >> 6) & 63, co = (idx >> 12) & 63, b = idx >> 18;
  float acc = bias[co];
  for (int ci = 0; ci < 64; ++ci) {
    for (int kh = 0; kh < 3; ++kh) {
      int hh = h + kh - 1;
      if ((unsigned)hh >= 64u) continue;
      for (int kw = 0; kw < 3; ++kw) {
        int ww = w + kw - 1;
        if ((unsigned)ww >= 64u) continue;
        float v = x[((b * 64 + ci) * 64 + hh) * 64 + ww];
        int wi = ((co * 64 + ci) * 3 + kh) * 3 + kw;
        float s1, c1; __sincosf(v, &s1, &c1);
        float c2 = c1 * c1 - s1 * s1, s2 = 2.f * s1 * c1;
        float c3 = c1 * c2 - s1 * s2, s3 = s1 * c2 + c1 * s2;
        float t = sb[wi] * (v / (1.f + __expf(-v)));
        t += ss[wi] * (cf[wi * 3] * c1 + cf[wi * 3 + 1] * c2 + cf[wi * 3 + 2] * c3 +
                       cf[(36864 + wi) * 3] * s1 + cf[(36864 + wi) * 3 + 1] * s2 +
                       cf[(36864 + wi) * 3 + 2] * s3);
        acc += t;
      }
    }
  }
  out[idx] = acc;
}

extern "C" void kernel_launch(void* const* d_in, const int* in_sizes, int n_in,
                              void* d_out, int out_size, void* d_ws, size_t ws_size,
                              hipStream_t stream) {
  const float* x = (const float*)d_in[0];
  const float* sb = (const float*)d_in[1];
  const float* ss = (const float*)d_in[2];
  const float* cf = (const float*)d_in[3];
  const float* bias = (const float*)d_in[4];
  float* out = (float*)d_out;

  const size_t NEED = 1u << 20;   // only wpk (516 KB)
  if (ws_size >= NEED) {
    unsigned short* wpk = (unsigned short*)d_ws;
    pack_w_k<<<1008, 256, 0, stream>>>(sb, ss, cf, wpk);
    (void)hipFuncSetAttribute((const void*)gemm_k,
                              hipFuncAttributeMaxDynamicSharedMemorySize, LDS_T2);
    gemm_k<<<dim3(32, 16), 256, LDS_T2, stream>>>(x, wpk, bias, out);
  } else {
    naive_k<<<32768, 256, 0, stream>>>(x, sb, ss, cf, bias, out);
  }
}

// Round 14
// 196.475 us; speedup vs baseline: 1.1898x; 1.1898x over previous
//
#include <hip/hip_runtime.h>

typedef __attribute__((ext_vector_type(8))) short bf16x8;
typedef __attribute__((ext_vector_type(4))) float f32x4;

#define FROW   4224                     // 66 cols * 64 B per LDS feature row
#define FBUF4  25344                    // 6 rows (4-row block + halo)
#define BTRIO  12288                    // 3 taps * 4096 B
#define LDS_T2 (2 * FBUF4 + 2 * BTRIO)  // 75264 B -> 2 blocks/CU

static __device__ __forceinline__ unsigned short f2bf(float f) {
  union { float f; unsigned u; } v; v.f = f;
  unsigned r = v.u + 0x7fffu + ((v.u >> 16) & 1u);
  return (unsigned short)(r >> 16);
}

static __device__ __forceinline__ void gload16(const void* g, void* l) {
  __builtin_amdgcn_global_load_lds(
      (const __attribute__((address_space(1))) void*)g,
      (__attribute__((address_space(3))) void*)l, 16, 0, 0);
}

// ---------------- kernel P: pack weights ----------------
// wpk: [it(126 = c2*9+tap)][co(64)][slot(4)][8ci] bf16, slot' = slot ^ ((co>>1)&3)
__global__ void pack_w_k(const float* __restrict__ sb, const float* __restrict__ ss,
                         const float* __restrict__ cf, unsigned short* __restrict__ wpk) {
  int idx = blockIdx.x * 256 + threadIdx.x;
  if (idx >= 126 * 64 * 32) return;
  int e = idx & 7;
  int q = (idx >> 3) & 3;
  int co = (idx >> 5) & 63;
  int rest = idx >> 11;
  int tap = rest % 9;
  int c2 = rest / 9;
  int c = c2 >> 1, half = c2 & 1;
  int ci = half * 32 + q * 8 + e;
  int kh = tap / 3, kw = tap % 3;
  int wi = ((co * 64 + ci) * 3 + kh) * 3 + kw;
  float v;
  if (c == 0) {
    v = sb[wi];
  } else {
    int s = (c - 1) / 3, g = (c - 1) % 3;
    v = cf[(s * 36864 + wi) * 3 + g] * ss[wi];
  }
  wpk[((c2 * 9 + tap) * 64 + co) * 32 + ((q ^ ((co >> 1) & 3)) << 3) + e] = f2bf(v);
}

// ---------------- kernel G: x-register-resident fused featgen + GEMM ----------------
// grid (32 b, 16 hg) = 512 blocks = 2/CU (LDS 75.3 KB). 4 waves; wave wid owns
// image row h0+wid: M=64 px x N=64 co, all 9 taps. The block's x window
// (6 rows x 64 ci x 64 w) lives in registers: 96 f32/thread, loaded ONCE in the
// prologue. Per chunk, features are computed from registers (no global loads on
// the K-loop critical path) and ds_written into the swizzled double buffer,
// 2 rows per kh phase. B staged from wpk as 3-tap trios via global_load_lds.
__global__ __launch_bounds__(256, 2) void gemm_k(
    const float* __restrict__ x, const unsigned short* __restrict__ wpk,
    const float* __restrict__ bias, float* __restrict__ out) {
  extern __shared__ __align__(16) char smem[];
  const int b = blockIdx.x;
  const int h0 = blockIdx.y * 4;
  const int tid = threadIdx.x;
  const int lane = tid & 63;
  const int wid = tid >> 6;          // 0..3
  const int l15 = lane & 15;
  const int lg = lane >> 4;
  const char* wpkB = (const char*)wpk;

  // featgen thread map: w = tid&63 (lane=w), fq = ci-quad-within-half = wid
  const int fw = tid & 63;
  const int fq = tid >> 6;
  const int fcol = fw + 1;                               // LDS col (halo 0/65)
  const int fsl16 = (fq ^ ((fcol >> 1) & 3)) << 4;       // swizzled slot byte-off
  const int fbase = fcol * 64 + fsl16;

  // zero never-staged bytes: halo cols + out-of-range rows (both feat buffers)
  for (int i = tid; i < 2 * FBUF4 / 4; i += 256) {
    int off = i * 4;
    int off2 = (off >= FBUF4) ? off - FBUF4 : off;
    int row = off2 / FROW;
    int cb = off2 - row * FROW;
    int hh = h0 - 1 + row;
    bool staged = ((unsigned)hh < 64u) && (cb >= 64) && (cb < 4160);
    if (!staged) ((int*)smem)[i] = 0;
  }

  // ---- prologue: load the block's x window into registers (96 f32) ----
  const float* xb = x + (size_t)(b * 64 + fq * 8) * 4096 + fw;
  float xr[6][2][8];
#pragma unroll
  for (int r = 0; r < 6; ++r) {
    int hh = h0 - 1 + r;
    if ((unsigned)hh < 64u) {
#pragma unroll
      for (int hf = 0; hf < 2; ++hf)
#pragma unroll
        for (int e = 0; e < 8; ++e)
          xr[r][hf][e] = xb[(size_t)(hf * 32 + e) * 4096 + hh * 64];
    } else {
#pragma unroll
      for (int hf = 0; hf < 2; ++hf)
#pragma unroll
        for (int e = 0; e < 8; ++e)
          xr[r][hf][e] = 0.0f;
    }
  }

  // hoisted swizzled LDS offsets
  int aoff[4][3], boff[4];
#pragma unroll
  for (int cf = 0; cf < 4; ++cf) {
#pragma unroll
    for (int kw = 0; kw < 3; ++kw) {
      int col = cf * 16 + l15 + kw;
      aoff[cf][kw] = col * 64 + ((lg ^ ((col >> 1) & 3)) << 4);
    }
    int co = cf * 16 + l15;
    boff[cf] = co * 64 + ((lg ^ ((co >> 1) & 3)) << 4);
  }

  // stage B trio for (chunk cn, kh khn) into bdst: 12 gload16 over 4 waves
#define STAGE_TRIO(cn, khn, bdst)                                                \
  _Pragma("unroll")                                                              \
  for (int i = 0; i < 3; ++i) {                                                  \
    int u = i * 4 + wid;                                                         \
    gload16(wpkB + (size_t)((cn) * 9 + (khn) * 3 + (u >> 2)) * 4096 +            \
                (u & 3) * 1024 + lane * 16,                                      \
            (bdst) + (u >> 2) * 4096 + (u & 3) * 1024);                          \
  }

  // featgen from registers: rows 2p,2p+1 of chunk cn (half H, compile-time) -> fdst
#define FEATGEN_P(cn, p, fdst, H)                                                \
  {                                                                              \
    const int c_ = (cn) >> 1;                                                    \
    _Pragma("unroll")                                                            \
    for (int rr = 0; rr < 2; ++rr) {                                             \
      const int r = (p) * 2 + rr;                                                \
      int hh = h0 - 1 + r;                                                       \
      if ((unsigned)hh < 64u) {                                                  \
        bf16x8 pk;                                                               \
        _Pragma("unroll")                                                        \
        for (int e = 0; e < 8; ++e) {                                            \
          float v = xr[r][H][e];                                                 \
          float val;                                                             \
          if (c_ == 0)      val = v / (1.0f + __expf(-v));                       \
          else if (c_ == 1) val = __cosf(v);                                     \
          else if (c_ == 2) val = __cosf(2.0f * v);                              \
          else if (c_ == 3) val = __cosf(3.0f * v);                              \
          else if (c_ == 4) val = __sinf(v);                                     \
          else if (c_ == 5) val = __sinf(2.0f * v);                              \
          else              val = __sinf(3.0f * v);                              \
          pk[e] = (short)f2bf(val);                                              \
        }                                                                        \
        *(bf16x8*)((fdst) + r * FROW + fbase) = pk;                              \
      }                                                                          \
    }                                                                            \
  }

  // prologue: features chunk 0 (half 0, all 3 phases) + B trio (0,0)
#pragma unroll
  for (int p = 0; p < 3; ++p) { FEATGEN_P(0, p, smem, 0) }
  STAGE_TRIO(0, 0, smem + 2 * FBUF4)
  __syncthreads();

  f32x4 acc[4][4];
#pragma unroll
  for (int cfi = 0; cfi < 4; ++cfi)
#pragma unroll
    for (int nf = 0; nf < 4; ++nf)
#pragma unroll
      for (int qq = 0; qq < 4; ++qq) acc[cfi][nf][qq] = 0.0f;

  for (int c2 = 0; c2 < 14; ++c2) {
    const char* f = smem + ((c2 & 1) ? FBUF4 : 0);
    char* fnext = smem + (((c2 + 1) & 1) ? FBUF4 : 0);
#pragma unroll
    for (int kh = 0; kh < 3; ++kh) {
      const int khg = c2 * 3 + kh;
      const char* bb = smem + 2 * FBUF4 + ((khg & 1) ? BTRIO : 0);
      if (khg < 41) {
        char* bnext = smem + 2 * FBUF4 + (((khg + 1) & 1) ? BTRIO : 0);
        const int cn = (khg + 1) / 3, khn = (khg + 1) % 3;
        STAGE_TRIO(cn, khn, bnext)
      }
      if (c2 < 13) {
        const int cn = c2 + 1;
        if (cn & 1) { FEATGEN_P(cn, kh, fnext, 1) }
        else        { FEATGEN_P(cn, kh, fnext, 0) }
      }

      const char* frow = f + (wid + kh) * FROW;
#pragma unroll
      for (int kw = 0; kw < 3; ++kw) {
        bf16x8 A[4], Bv[4];
#pragma unroll
        for (int cfi = 0; cfi < 4; ++cfi)
          A[cfi] = *(const bf16x8*)(frow + aoff[cfi][kw]);
#pragma unroll
        for (int nf = 0; nf < 4; ++nf)
          Bv[nf] = *(const bf16x8*)(bb + kw * 4096 + boff[nf]);
#pragma unroll
        for (int cfi = 0; cfi < 4; ++cfi)
#pragma unroll
          for (int nf = 0; nf < 4; ++nf)
            acc[cfi][nf] = __builtin_amdgcn_mfma_f32_16x16x32_bf16(
                A[cfi], Bv[nf], acc[cfi][nf], 0, 0, 0);
      }
      __syncthreads();
    }
  }
#undef STAGE_TRIO
#undef FEATGEN_P

  // epilogue: direct store. C/D: col(l15)=co, row=lg*4+reg = pixel w
  const int h = h0 + wid;
#pragma unroll
  for (int cfi = 0; cfi < 4; ++cfi) {
    int w4 = cfi * 16 + (lg << 2);
#pragma unroll
    for (int nf = 0; nf < 4; ++nf) {
      int co = nf * 16 + l15;
      float bv = bias[co];
      f32x4 v = acc[cfi][nf];
      f32x4 res;
      res[0] = v[0] + bv; res[1] = v[1] + bv; res[2] = v[2] + bv; res[3] = v[3] + bv;
      *(f32x4*)(out + ((size_t)(b * 64 + co) * 64 + h) * 64 + w4) = res;
    }
  }
}

// ---------------- fallback: naive fp32 direct (if ws too small) ----------------
__global__ void naive_k(const float* __restrict__ x, const float* __restrict__ sb,
                        const float* __restrict__ ss, const float* __restrict__ cf,
                        const float* __restrict__ bias, float* __restrict__ out) {
  int idx = blockIdx.x * 256 + threadIdx.x;
  if (idx >= 32 * 64 * 64 * 64) return;
  int w = idx & 63, h = (idx >> 6) & 63, co = (idx >> 12) & 63, b = idx >> 18;
  float acc = bias[co];
  for (int ci = 0; ci < 64; ++ci) {
    for (int kh = 0; kh < 3; ++kh) {
      int hh = h + kh - 1;
      if ((unsigned)hh >= 64u) continue;
      for (int kw = 0; kw < 3; ++kw) {
        int ww = w + kw - 1;
        if ((unsigned)ww >= 64u) continue;
        float v = x[((b * 64 + ci) * 64 + hh) * 64 + ww];
        int wi = ((co * 64 + ci) * 3 + kh) * 3 + kw;
        float s1, c1; __sincosf(v, &s1, &c1);
        float c2 = c1 * c1 - s1 * s1, s2 = 2.f * s1 * c1;
        float c3 = c1 * c2 - s1 * s2, s3 = s1 * c2 + c1 * s2;
        float t = sb[wi] * (v / (1.f + __expf(-v)));
        t += ss[wi] * (cf[wi * 3] * c1 + cf[wi * 3 + 1] * c2 + cf[wi * 3 + 2] * c3 +
                       cf[(36864 + wi) * 3] * s1 + cf[(36864 + wi) * 3 + 1] * s2 +
                       cf[(36864 + wi) * 3 + 2] * s3);
        acc += t;
      }
    }
  }
  out[idx] = acc;
}

extern "C" void kernel_launch(void* const* d_in, const int* in_sizes, int n_in,
                              void* d_out, int out_size, void* d_ws, size_t ws_size,
                              hipStream_t stream) {
  const float* x = (const float*)d_in[0];
  const float* sb = (const float*)d_in[1];
  const float* ss = (const float*)d_in[2];
  const float* cf = (const float*)d_in[3];
  const float* bias = (const float*)d_in[4];
  float* out = (float*)d_out;

  const size_t NEED = 1u << 20;   // only wpk (516 KB)
  if (ws_size >= NEED) {
    unsigned short* wpk = (unsigned short*)d_ws;
    pack_w_k<<<1008, 256, 0, stream>>>(sb, ss, cf, wpk);
    (void)hipFuncSetAttribute((const void*)gemm_k,
                              hipFuncAttributeMaxDynamicSharedMemorySize, LDS_T2);
    gemm_k<<<dim3(32, 16), 256, LDS_T2, stream>>>(x, wpk, bias, out);
  } else {
    naive_k<<<32768, 256, 0, stream>>>(x, sb, ss, cf, bias, out);
  }
}